// Round 5
// baseline (819.333 us; speedup 1.0000x reference)
//
#include <hip/hip_runtime.h>
#include <hip/hip_cooperative_groups.h>
#include <math.h>

namespace cg = cooperative_groups;

#define DIM   1024
#define HALF  512
#define NROWS 65536
#define NB    512      // grid blocks; 2/CU guaranteed resident via launch_bounds
#define RPB   128      // rows of k_init per block

// ---- ws float offsets (no memset needed; everything fully written) ----
#define OFF_QACC  0                       // [512]
#define OFF_PVEC  512                     // [1024]
#define OFF_PSTAT 1536                    // float2[NB] = 1024 floats
#define OFF_SV    2560                    // [65536]
#define OFF_INVN  (OFF_SV + NROWS)        // [65536]
#define OFF_PESUM (OFF_INVN + NROWS)      // [NB]
#define OFF_PW    (OFF_PESUM + NB)        // [NB*DIM] = 2 MB
#define OFF_WACC  (OFF_PW + NB * DIM)     // [1024]
#define OFF_OV    (OFF_WACC + DIM)        // [1024]

__device__ __forceinline__ void f4acc(float4& a, float c, const float4& m) {
    a.x += c * m.x; a.y += c * m.y; a.z += c * m.z; a.w += c * m.w;
}

__global__ __launch_bounds__(256, 2)
void k_fused(const float* __restrict__ q_init, const float* __restrict__ k_init,
             const float* __restrict__ Wq, const float* __restrict__ bq,
             const float* __restrict__ Wk, const float* __restrict__ Wv,
             const float* __restrict__ bv, const float* __restrict__ Wm,
             const float* __restrict__ bm, const float* __restrict__ gamma,
             float* __restrict__ ws, float* __restrict__ out)
{
    cg::grid_group grid = cg::this_grid();
    __shared__ float  s_f[1280];
    __shared__ float4 s_v4[256];
    const int t = threadIdx.x;
    const int b = blockIdx.x;
    const int wave = t >> 6, lane = t & 63;

    float*  qacc  = ws + OFF_QACC;
    float*  pvec  = ws + OFF_PVEC;
    float2* pstat = (float2*)(ws + OFF_PSTAT);
    float*  svals = ws + OFF_SV;
    float*  invn  = ws + OFF_INVN;
    float*  pesum = ws + OFF_PESUM;
    float*  pw    = ws + OFF_PW;
    float*  wacc  = ws + OFF_WACC;
    float*  ovacc = ws + OFF_OV;

    // ---------- phase 0a: qacc = l2norm(q_init) @ Wq   (blocks 0..127) ----------
    if (b < HALF / 4) {
        float sq = 0.f;
        #pragma unroll
        for (int i = 0; i < 4; ++i) {
            float v = q_init[t + i * 256];
            s_f[t + i * 256] = v;
            sq += v * v;
        }
        s_f[1024 + t] = sq;
        __syncthreads();
        for (int s = 128; s > 0; s >>= 1) {
            if (t < s) s_f[1024 + t] += s_f[1024 + t + s];
            __syncthreads();
        }
        float inv = 1.0f / fmaxf(sqrtf(s_f[1024]), 1e-12f);
        const float4* W4 = (const float4*)Wq;
        float4 acc = make_float4(0.f, 0.f, 0.f, 0.f);
        #pragma unroll
        for (int i = 0; i < 4; ++i) {
            int r = t + i * 256;
            f4acc(acc, s_f[r] * inv, W4[(size_t)r * (HALF / 4) + b]);
        }
        s_v4[t] = acc;
        __syncthreads();
        for (int s = 128; s > 0; s >>= 1) {
            if (t < s) {
                s_v4[t].x += s_v4[t + s].x; s_v4[t].y += s_v4[t + s].y;
                s_v4[t].z += s_v4[t + s].z; s_v4[t].w += s_v4[t + s].w;
            }
            __syncthreads();
        }
        if (t == 0) ((float4*)qacc)[b] = s_v4[0];
    }
    grid.sync();

    // ---------- phase 0b: pvec[d] = Wk[d,:] . (qacc + bq)   (blocks 0..255) ----------
    if (b < 256) {
        if (t < 128) {
            float4 qa = ((const float4*)qacc)[t];
            float4 bb = ((const float4*)bq)[t];
            s_v4[t] = make_float4(qa.x + bb.x, qa.y + bb.y, qa.z + bb.z, qa.w + bb.w);
        }
        __syncthreads();
        int d = b * 4 + wave;
        const float4* row4 = (const float4*)(Wk + (size_t)d * HALF);
        float acc = 0.f;
        #pragma unroll
        for (int i = 0; i < 2; ++i) {
            float4 a = row4[lane + 64 * i];
            float4 p = s_v4[lane + 64 * i];
            acc += a.x * p.x + a.y * p.y + a.z * p.z + a.w * p.w;
        }
        #pragma unroll
        for (int o = 32; o > 0; o >>= 1) acc += __shfl_down(acc, o);
        if (lane == 0) pvec[d] = acc;
    }
    grid.sync();

    // ---------- phase 1: scores + inv norms + per-block stats ----------
    s_v4[t] = ((const float4*)pvec)[t];
    __syncthreads();
    {
        int base = b * RPB + wave * 32;
        float wsum = 0.f, wssq = 0.f;
        for (int g2 = 0; g2 < 8; ++g2) {
            int row0 = base + g2 * 4;
            const float4* k4 = (const float4*)k_init + (size_t)row0 * 256 + lane;
            float4 v[16];
            #pragma unroll
            for (int r = 0; r < 4; ++r)
                #pragma unroll
                for (int i = 0; i < 4; ++i)
                    v[r * 4 + i] = k4[r * 256 + i * 64];
            float d4[4] = {0, 0, 0, 0}, q4[4] = {0, 0, 0, 0};
            #pragma unroll
            for (int r = 0; r < 4; ++r) {
                #pragma unroll
                for (int i = 0; i < 4; ++i) {
                    float4 a = v[r * 4 + i];
                    float4 p = s_v4[lane + i * 64];
                    d4[r] += a.x * p.x + a.y * p.y + a.z * p.z + a.w * p.w;
                    q4[r] += a.x * a.x + a.y * a.y + a.z * a.z + a.w * a.w;
                }
            }
            #pragma unroll
            for (int o = 32; o > 0; o >>= 1) {
                #pragma unroll
                for (int r = 0; r < 4; ++r) {
                    d4[r] += __shfl_down(d4[r], o);
                    q4[r] += __shfl_down(q4[r], o);
                }
            }
            if (lane == 0) {
                float i0 = 1.0f / fmaxf(sqrtf(q4[0]), 1e-12f);
                float i1 = 1.0f / fmaxf(sqrtf(q4[1]), 1e-12f);
                float i2 = 1.0f / fmaxf(sqrtf(q4[2]), 1e-12f);
                float i3 = 1.0f / fmaxf(sqrtf(q4[3]), 1e-12f);
                float s0 = d4[0] * i0, s1 = d4[1] * i1, s2 = d4[2] * i2, s3 = d4[3] * i3;
                *(float4*)(svals + row0) = make_float4(s0, s1, s2, s3);
                *(float4*)(invn + row0)  = make_float4(i0, i1, i2, i3);
                wsum += s0 + s1 + s2 + s3;
                wssq += s0 * s0 + s1 * s1 + s2 * s2 + s3 * s3;
            }
        }
        if (lane == 0) { s_f[wave] = wsum; s_f[4 + wave] = wssq; }
        __syncthreads();
        if (t == 0)
            pstat[b] = make_float2(s_f[0] + s_f[1] + s_f[2] + s_f[3],
                                   s_f[4] + s_f[5] + s_f[6] + s_f[7]);
    }
    grid.sync();

    // ---------- interlude: every block reduces pstat -> mean, rstd ----------
    {
        float2 pa = pstat[t], pb = pstat[t + 256];
        s_f[t] = pa.x + pb.x;
        s_f[256 + t] = pa.y + pb.y;
        __syncthreads();
        for (int s = 128; s > 0; s >>= 1) {
            if (t < s) { s_f[t] += s_f[t + s]; s_f[256 + t] += s_f[256 + t + s]; }
            __syncthreads();
        }
        if (t == 0) {
            float mean = s_f[0] / (float)NROWS;
            float var  = (s_f[256] - (float)NROWS * mean * mean) / (float)(NROWS - 1);
            s_f[512] = mean;
            s_f[513] = 1.0f / (sqrtf(fmaxf(var, 0.0f)) + 1e-8f);
        }
        __syncthreads();
    }
    float mean = s_f[512], rstd = s_f[513];

    // ---------- phase 2: pw[b] = sum e_r*invn_r*K[r,:]  (newest rows first) ----------
    {
        int r0 = b * RPB;
        const float4* K4 = (const float4*)k_init + (size_t)r0 * 256 + t;
        float4 acc = make_float4(0.f, 0.f, 0.f, 0.f);
        float esum = 0.f;
        for (int gb = 15; gb >= 0; --gb) {
            float4 m[8];
            #pragma unroll
            for (int r = 0; r < 8; ++r) m[r] = K4[(size_t)(gb * 8 + r) * 256];
            #pragma unroll
            for (int r = 0; r < 8; ++r) {
                int ri = r0 + gb * 8 + r;
                float z = (svals[ri] - mean) * rstd;
                z = fminf(fmaxf(z, -10.0f), 10.0f);
                float e = expf(z);
                esum += e;
                f4acc(acc, e * invn[ri], m[r]);
            }
        }
        ((float4*)pw)[(size_t)b * 256 + t] = acc;
        if (t == 0) pesum[b] = esum;
    }
    grid.sync();

    // ---------- phase 3: fold pw -> wacc = w / sum(exp)   (blocks 0..255) ----------
    if (b < 256) {
        const float4* pw4 = (const float4*)pw;
        float4 a0 = pw4[(size_t)t * 256 + b];
        float4 a1 = pw4[(size_t)(t + 256) * 256 + b];
        s_v4[t] = make_float4(a0.x + a1.x, a0.y + a1.y, a0.z + a1.z, a0.w + a1.w);
        s_f[t] = pesum[t] + pesum[t + 256];
        __syncthreads();
        for (int s = 128; s > 0; s >>= 1) {
            if (t < s) {
                s_v4[t].x += s_v4[t + s].x; s_v4[t].y += s_v4[t + s].y;
                s_v4[t].z += s_v4[t + s].z; s_v4[t].w += s_v4[t + s].w;
                s_f[t] += s_f[t + s];
            }
            __syncthreads();
        }
        if (t == 0) {
            float inv = 1.0f / s_f[0];
            float4 w = s_v4[0];
            ((float4*)wacc)[b] = make_float4(w.x * inv, w.y * inv, w.z * inv, w.w * inv);
        }
    }
    grid.sync();

    // ---------- phase 4: ovacc = wacc @ Wv   (blocks 0..255) ----------
    if (b < 256) {
        const float4* W4 = (const float4*)Wv;
        float4 acc = make_float4(0.f, 0.f, 0.f, 0.f);
        #pragma unroll
        for (int i = 0; i < 4; ++i) {
            int r = t + i * 256;
            f4acc(acc, wacc[r], W4[(size_t)r * 256 + b]);
        }
        s_v4[t] = acc;
        __syncthreads();
        for (int s = 128; s > 0; s >>= 1) {
            if (t < s) {
                s_v4[t].x += s_v4[t + s].x; s_v4[t].y += s_v4[t + s].y;
                s_v4[t].z += s_v4[t + s].z; s_v4[t].w += s_v4[t + s].w;
            }
            __syncthreads();
        }
        if (t == 0) ((float4*)ovacc)[b] = s_v4[0];
    }
    grid.sync();

    // ---------- phase 5: out = gate(q_init, (ovacc+bv) @ Wm + bm)   (blocks 0..255) ----------
    if (b < 256) {
        const float4* W4 = (const float4*)Wm;
        float4 acc = make_float4(0.f, 0.f, 0.f, 0.f);
        #pragma unroll
        for (int i = 0; i < 4; ++i) {
            int r = t + i * 256;
            f4acc(acc, ovacc[r] + bv[r], W4[(size_t)r * 256 + b]);
        }
        s_v4[t] = acc;
        __syncthreads();
        for (int s = 128; s > 0; s >>= 1) {
            if (t < s) {
                s_v4[t].x += s_v4[t + s].x; s_v4[t].y += s_v4[t + s].y;
                s_v4[t].z += s_v4[t + s].z; s_v4[t].w += s_v4[t + s].w;
            }
            __syncthreads();
        }
        if (t == 0) {
            float gv = 1.0f / (1.0f + expf(-gamma[0]));
            float4 qv  = ((const float4*)q_init)[b];
            float4 bmv = ((const float4*)bm)[b];
            float4 red = s_v4[0];
            ((float4*)out)[b] = make_float4(
                gv * qv.x + (1.0f - gv) * (red.x + bmv.x),
                gv * qv.y + (1.0f - gv) * (red.y + bmv.y),
                gv * qv.z + (1.0f - gv) * (red.z + bmv.z),
                gv * qv.w + (1.0f - gv) * (red.w + bmv.w));
        }
    }
}

extern "C" void kernel_launch(void* const* d_in, const int* in_sizes, int n_in,
                              void* d_out, int out_size, void* d_ws, size_t ws_size,
                              hipStream_t stream) {
    const float* q_init = (const float*)d_in[0];
    const float* k_init = (const float*)d_in[1];
    const float* Wq     = (const float*)d_in[2];
    const float* bq     = (const float*)d_in[3];
    const float* Wk     = (const float*)d_in[4];
    // d_in[5] = bk: constant shift of all scores -> cancels in standardization
    const float* Wv     = (const float*)d_in[6];
    const float* bv     = (const float*)d_in[7];
    const float* Wm     = (const float*)d_in[8];
    const float* bm     = (const float*)d_in[9];
    const float* gamma  = (const float*)d_in[10];
    float* out = (float*)d_out;
    float* ws  = (float*)d_ws;

    void* args[] = { &q_init, &k_init, &Wq, &bq, &Wk, &Wv, &bv, &Wm, &bm,
                     &gamma, &ws, &out };
    hipLaunchCooperativeKernel((void*)k_fused, dim3(NB), dim3(256), args, 0, stream);
}

// Round 6
// 479.687 us; speedup vs baseline: 1.7081x; 1.7081x over previous
//
#include <hip/hip_runtime.h>
#include <math.h>

#define DIM   1024
#define HALF  512
#define NROWS 65536
#define SBLK  4096   // k_scores blocks: 16 rows each (4 waves x 4 rows, quarter-wave/row)
#define WBLK  4096   // k_wsum blocks: 16 rows each
#define WF1   64     // fold-1 blocks (WBLK/WF1 = 64 partials each)

// ---- workspace layout (float offsets), atomic-free, no memset needed ----
#define OFF_SCAL   0                         // [0]=mean [1]=rstd
#define OFF_QACC   (OFF_SCAL + 8)            // [512]
#define OFF_PVEC   (OFF_QACC + HALF)         // [1024]
#define OFF_PSTAT  (OFF_PVEC + DIM)          // float2[SBLK]
#define OFF_S      (OFF_PSTAT + 2*SBLK)      // [65536]
#define OFF_INVN   (OFF_S + NROWS)           // [65536]
#define OFF_PESUM  (OFF_INVN + NROWS)        // [WBLK]
#define OFF_PW     (OFF_PESUM + WBLK)        // [WBLK*DIM] = 16 MB
#define OFF_P2     (OFF_PW + (size_t)WBLK*DIM) // [WF1*DIM]
#define OFF_WACC   (OFF_P2 + WF1*DIM)        // [1024]
#define OFF_OVACC  (OFF_WACC + DIM)          // [1024]

// Fused: qn = l2norm(q_init); qacc[c4] = sum_r qn[r]*Wq[r][c4]. 128 blocks.
__global__ void k_prep(const float* __restrict__ q_init,
                       const float* __restrict__ Wq,
                       float* __restrict__ qacc) {
    __shared__ float qs[DIM];
    __shared__ float4 red4[256];
    __shared__ float red[256];
    int t = threadIdx.x, c4 = blockIdx.x;
    float sq = 0.f;
    #pragma unroll
    for (int i = 0; i < 4; ++i) {
        float v = q_init[t + i * 256];
        qs[t + i * 256] = v;
        sq += v * v;
    }
    red[t] = sq;
    __syncthreads();
    for (int s = 128; s > 0; s >>= 1) {
        if (t < s) red[t] += red[t + s];
        __syncthreads();
    }
    float inv = 1.0f / fmaxf(sqrtf(red[0]), 1e-12f);
    const float4* W4 = (const float4*)Wq;
    float4 acc = make_float4(0.f, 0.f, 0.f, 0.f);
    #pragma unroll
    for (int i = 0; i < 4; ++i) {
        int r = t + i * 256;
        float c = qs[r] * inv;
        float4 m = W4[(size_t)r * (HALF / 4) + c4];
        acc.x += c * m.x; acc.y += c * m.y; acc.z += c * m.z; acc.w += c * m.w;
    }
    red4[t] = acc;
    __syncthreads();
    for (int s = 128; s > 0; s >>= 1) {
        if (t < s) {
            red4[t].x += red4[t + s].x; red4[t].y += red4[t + s].y;
            red4[t].z += red4[t + s].z; red4[t].w += red4[t + s].w;
        }
        __syncthreads();
    }
    if (t == 0) ((float4*)qacc)[c4] = red4[0];
}

// pvec[d] = Wk[d,:] . (qacc + bq); one wave per row d. 256 blocks.
__global__ void k_pvec(const float* __restrict__ Wk,
                       const float* __restrict__ qacc,
                       const float* __restrict__ bq,
                       float* __restrict__ pvec) {
    __shared__ float q[HALF];
    int t = threadIdx.x; // 256
    for (int j = t; j < HALF; j += 256) q[j] = qacc[j] + bq[j];
    __syncthreads();
    int wave = t >> 6, lane = t & 63;
    int d = blockIdx.x * 4 + wave;
    const float* row = Wk + (size_t)d * HALF;
    float acc = 0.f;
    #pragma unroll
    for (int j0 = 0; j0 < HALF; j0 += 64) acc += row[j0 + lane] * q[j0 + lane];
    #pragma unroll
    for (int o = 32; o > 0; o >>= 1) acc += __shfl_down(acc, o);
    if (lane == 0) pvec[d] = acc;
}

// Pass 1, quarter-wave-per-row layout: 16 lanes own a whole row.
// pvec slice lives in registers; zero LDS in the hot loop; 4-level shuffle reduce.
// Grid = SBLK blocks x 256 thr (16 rows/block).
__global__ __launch_bounds__(256)
void k_scores(const float* __restrict__ K,
              const float* __restrict__ pvec,
              float* __restrict__ svals,
              float* __restrict__ invn,
              float2* __restrict__ pstat) {
    __shared__ float sb[8];
    int t = threadIdx.x;
    int wave = t >> 6, lane = t & 63;
    int sub = lane & 15;           // float4-slice index within row
    int row = blockIdx.x * 16 + wave * 4 + (lane >> 4);

    const float4* p4 = (const float4*)pvec;
    float4 p[16];
    #pragma unroll
    for (int i = 0; i < 16; ++i) p[i] = p4[sub + 16 * i];

    const float4* k4 = (const float4*)K + (size_t)row * 256 + sub;
    float dot = 0.f, sq = 0.f;
    #pragma unroll
    for (int i = 0; i < 16; ++i) {
        float4 a = k4[16 * i];
        dot += a.x * p[i].x + a.y * p[i].y + a.z * p[i].z + a.w * p[i].w;
        sq  += a.x * a.x + a.y * a.y + a.z * a.z + a.w * a.w;
    }
    #pragma unroll
    for (int o = 8; o > 0; o >>= 1) {
        dot += __shfl_down(dot, o);
        sq  += __shfl_down(sq, o);
    }
    float sv = 0.f;
    if (sub == 0) {
        float inv = 1.0f / fmaxf(sqrtf(sq), 1e-12f);
        sv = dot * inv;
        svals[row] = sv;
        invn[row]  = inv;
    }
    // block stats: sum s, s^2 across the 4 row-leaders (lanes 0,16,32,48), then waves
    float ss = (sub == 0) ? sv : 0.f;
    float qq = (sub == 0) ? sv * sv : 0.f;
    ss += __shfl_down(ss, 16); qq += __shfl_down(qq, 16);
    ss += __shfl_down(ss, 32); qq += __shfl_down(qq, 32);
    if (lane == 0) { sb[wave] = ss; sb[4 + wave] = qq; }
    __syncthreads();
    if (t == 0)
        pstat[blockIdx.x] = make_float2(sb[0] + sb[1] + sb[2] + sb[3],
                                        sb[4] + sb[5] + sb[6] + sb[7]);
}

// Reduce SBLK partial stats -> scal[0]=mean, scal[1]=rstd. 1 block x 1024.
__global__ void k_redstats(const float2* __restrict__ pstat, float* __restrict__ scal) {
    __shared__ float rs[1024], rq[1024];
    int t = threadIdx.x;
    float s = 0.f, q = 0.f;
    for (int i = t; i < SBLK; i += 1024) {
        float2 p = pstat[i];
        s += p.x; q += p.y;
    }
    rs[t] = s; rq[t] = q;
    __syncthreads();
    for (int k = 512; k > 0; k >>= 1) {
        if (t < k) { rs[t] += rs[t + k]; rq[t] += rq[t + k]; }
        __syncthreads();
    }
    if (t == 0) {
        float mean = rs[0] / (float)NROWS;
        float var  = (rq[0] - (float)NROWS * mean * mean) / (float)(NROWS - 1);
        scal[0] = mean;
        scal[1] = 1.0f / (sqrtf(fmaxf(var, 0.0f)) + 1e-8f);
    }
}

// Pass 2 (coeff fused): block b (reverse order for L3 LRU) handles 16 rows.
// Private partial column sums, stored — no atomics. Grid = WBLK x 256.
__global__ __launch_bounds__(256)
void k_wsum(const float* __restrict__ K,
            const float* __restrict__ svals,
            const float* __restrict__ invn,
            const float* __restrict__ scal,
            float* __restrict__ pw,
            float* __restrict__ pesum) {
    int t = threadIdx.x;
    int b = (int)gridDim.x - 1 - (int)blockIdx.x;
    int r0 = b * 16;
    float mean = scal[0], rstd = scal[1];
    const float4* M4 = (const float4*)K + (size_t)r0 * 256 + t;
    float4 acc = make_float4(0.f, 0.f, 0.f, 0.f);
    float esum = 0.f;
    #pragma unroll
    for (int rb = 0; rb < 16; rb += 4) {
        float4 m[4];
        #pragma unroll
        for (int r = 0; r < 4; ++r) m[r] = M4[(size_t)(rb + r) * 256];
        #pragma unroll
        for (int r = 0; r < 4; ++r) {
            int ri = r0 + rb + r;
            float z = (svals[ri] - mean) * rstd;
            z = fminf(fmaxf(z, -10.0f), 10.0f);
            float e = expf(z);
            esum += e;
            float c = e * invn[ri];
            acc.x += c * m[r].x; acc.y += c * m[r].y;
            acc.z += c * m[r].z; acc.w += c * m[r].w;
        }
    }
    ((float4*)pw)[(size_t)b * 256 + t] = acc;
    if (t == 0) pesum[b] = esum;
}

// Fold WBLK partials -> WF1 partials. WF1 blocks x 256 thr.
__global__ void k_wfold(const float* __restrict__ pw, float* __restrict__ p2) {
    int t = threadIdx.x, b = blockIdx.x;
    const float4* pw4 = (const float4*)pw;
    float4 acc = make_float4(0.f, 0.f, 0.f, 0.f);
    for (int p = 0; p < WBLK / WF1; ++p) {
        float4 m = pw4[(size_t)(b * (WBLK / WF1) + p) * 256 + t];
        acc.x += m.x; acc.y += m.y; acc.z += m.z; acc.w += m.w;
    }
    ((float4*)p2)[b * 256 + t] = acc;
}

// Fold WF1 partials + reduce pesum[WBLK] -> wacc = w / sum(exp). 1 block x 1024.
__global__ void k_wreduce(const float* __restrict__ p2,
                          const float* __restrict__ pesum,
                          float* __restrict__ wacc) {
    __shared__ float red[1024];
    int t = threadIdx.x;
    float es = 0.f;
    for (int i = t; i < WBLK; i += 1024) es += pesum[i];
    red[t] = es;
    __syncthreads();
    for (int s = 512; s > 0; s >>= 1) {
        if (t < s) red[t] += red[t + s];
        __syncthreads();
    }
    float inv = 1.0f / red[0];
    float acc = 0.f;
    #pragma unroll
    for (int b = 0; b < WF1; ++b) acc += p2[b * DIM + t];
    wacc[t] = acc * inv;
}

// Column matvec: out[c4] = sum_r coeff[r] * M[r][c4]. 256 blocks x 256 thr.
__global__ void k_mv(const float* __restrict__ M,
                     const float* __restrict__ coeff,
                     float* __restrict__ out) {
    __shared__ float4 red[256];
    int t = threadIdx.x, c4 = blockIdx.x;
    const float4* M4 = (const float4*)M;
    float4 acc = make_float4(0.f, 0.f, 0.f, 0.f);
    #pragma unroll
    for (int i = 0; i < 4; ++i) {
        int r = t + i * 256;
        float c = coeff[r];
        float4 m = M4[(size_t)r * (DIM / 4) + c4];
        acc.x += c * m.x; acc.y += c * m.y; acc.z += c * m.z; acc.w += c * m.w;
    }
    red[t] = acc;
    __syncthreads();
    for (int s = 128; s > 0; s >>= 1) {
        if (t < s) {
            red[t].x += red[t + s].x; red[t].y += red[t + s].y;
            red[t].z += red[t + s].z; red[t].w += red[t + s].w;
        }
        __syncthreads();
    }
    if (t == 0) ((float4*)out)[c4] = red[0];
}

// Same + final gate epilogue. 256 blocks x 256 thr.
__global__ void k_mv_final(const float* __restrict__ M,
                           const float* __restrict__ coeff,
                           const float* __restrict__ cbias,
                           const float* __restrict__ q_init,
                           const float* __restrict__ bm,
                           const float* __restrict__ gamma,
                           float* __restrict__ out) {
    __shared__ float4 red[256];
    int t = threadIdx.x, c4 = blockIdx.x;
    const float4* M4 = (const float4*)M;
    float4 acc = make_float4(0.f, 0.f, 0.f, 0.f);
    #pragma unroll
    for (int i = 0; i < 4; ++i) {
        int r = t + i * 256;
        float c = coeff[r] + cbias[r];
        float4 m = M4[(size_t)r * (DIM / 4) + c4];
        acc.x += c * m.x; acc.y += c * m.y; acc.z += c * m.z; acc.w += c * m.w;
    }
    red[t] = acc;
    __syncthreads();
    for (int s = 128; s > 0; s >>= 1) {
        if (t < s) {
            red[t].x += red[t + s].x; red[t].y += red[t + s].y;
            red[t].z += red[t + s].z; red[t].w += red[t + s].w;
        }
        __syncthreads();
    }
    if (t == 0) {
        float g = 1.0f / (1.0f + expf(-gamma[0]));
        float4 qv  = ((const float4*)q_init)[c4];
        float4 bmv = ((const float4*)bm)[c4];
        ((float4*)out)[c4] = make_float4(
            g * qv.x + (1.0f - g) * (red[0].x + bmv.x),
            g * qv.y + (1.0f - g) * (red[0].y + bmv.y),
            g * qv.z + (1.0f - g) * (red[0].z + bmv.z),
            g * qv.w + (1.0f - g) * (red[0].w + bmv.w));
    }
}

extern "C" void kernel_launch(void* const* d_in, const int* in_sizes, int n_in,
                              void* d_out, int out_size, void* d_ws, size_t ws_size,
                              hipStream_t stream) {
    const float* q_init = (const float*)d_in[0];
    const float* k_init = (const float*)d_in[1];
    const float* Wq     = (const float*)d_in[2];
    const float* bq     = (const float*)d_in[3];
    const float* Wk     = (const float*)d_in[4];
    // d_in[5] = bk: constant shift of all scores -> cancels in standardization
    const float* Wv     = (const float*)d_in[6];
    const float* bv     = (const float*)d_in[7];
    const float* Wm     = (const float*)d_in[8];
    const float* bm     = (const float*)d_in[9];
    const float* gamma  = (const float*)d_in[10];
    float* out = (float*)d_out;
    float* ws  = (float*)d_ws;

    float*  scal   = ws + OFF_SCAL;
    float*  qacc   = ws + OFF_QACC;
    float*  pvec   = ws + OFF_PVEC;
    float2* pstat  = (float2*)(ws + OFF_PSTAT);
    float*  svals  = ws + OFF_S;
    float*  invn   = ws + OFF_INVN;
    float*  pesum  = ws + OFF_PESUM;
    float*  pw     = ws + OFF_PW;
    float*  p2     = ws + OFF_P2;
    float*  wacc   = ws + OFF_WACC;
    float*  ovacc  = ws + OFF_OVACC;

    // q = l2norm(q_init) @ Wq (bq folded in at k_pvec)
    k_prep<<<HALF / 4, 256, 0, stream>>>(q_init, Wq, qacc);
    // pvec = Wk @ (q + bq)
    k_pvec<<<DIM / 4, 256, 0, stream>>>(Wk, qacc, bq, pvec);
    // pass 1: scores + inv norms + per-block stats partials (quarter-wave rows)
    k_scores<<<SBLK, 256, 0, stream>>>(k_init, pvec, svals, invn, pstat);
    k_redstats<<<1, 1024, 0, stream>>>(pstat, scal);
    // pass 2 (coeff fused, reverse order): private partials
    k_wsum<<<WBLK, 256, 0, stream>>>(k_init, svals, invn, scal, pw, pesum);
    k_wfold<<<WF1, 256, 0, stream>>>(pw, p2);
    k_wreduce<<<1, 1024, 0, stream>>>(p2, pesum, wacc);
    // ov = w @ Wv ; out = gate(q_init, (ov + bv) @ Wm + bm)
    k_mv<<<DIM / 4, 256, 0, stream>>>(Wv, wacc, ovacc);
    k_mv_final<<<DIM / 4, 256, 0, stream>>>(Wm, ovacc, bv, q_init, bm, gamma, out);
}